// Round 1
// 526.777 us; speedup vs baseline: 1.1729x; 1.1729x over previous
//
#include <hip/hip_runtime.h>

typedef unsigned short u16;
typedef unsigned int   u32;
typedef _Float16 f16x8 __attribute__((ext_vector_type(8)));
typedef float  f32x4  __attribute__((ext_vector_type(4)));
typedef int    i32x4  __attribute__((ext_vector_type(4)));
typedef u32    u32x2  __attribute__((ext_vector_type(2)));

#define Bn 8
#define Sn 96
#define Tn 96
#define Hn 64
#define H2n 128
#define STRB 144           // state row stride BYTES (72 u16), 16B-aligned
#define ARRB 16384         // padded array stride bytes (96*144=13824 used) -> scalar parity fold
#define LDSB (8*ARRB)      // 131072 B: 2 dep x 2 stream x 2 parity

__device__ __forceinline__ int imax(int a, int b){ return a > b ? a : b; }
__device__ __forceinline__ int imin(int a, int b){ return a < b ? a : b; }

__device__ __forceinline__ u32 pack2f16(float a, float b){
  _Float16 ha = (_Float16)a, hb = (_Float16)b;    // v_cvt_f16_f32 (RNE)
  return (u32)__builtin_bit_cast(u16, ha) | ((u32)__builtin_bit_cast(u16, hb) << 16);
}
// tanh(x) = 1 - 2/(e^{2x}+1), e^{2x} = exp2(x*2*log2e). 7 VALU ops (was 9).
__device__ __forceinline__ float fast_tanh(float x){
  float y = fminf(fmaxf(x * 2.88539008f, -30.f), 30.f);
  float e = __builtin_amdgcn_exp2f(y);
  return __builtin_fmaf(-2.f, __builtin_amdgcn_rcpf(e + 1.f), 1.f);
}
// Workgroup barrier WITHOUT the vmcnt(0) drain __syncthreads() emits:
// only LDS ordering is needed between rounds (out write-only, px read-only).
__device__ __forceinline__ void barrier_lds_only(){
  asm volatile("s_waitcnt vmcnt(63) expcnt(7) lgkmcnt(0)\n\ts_barrier" ::: "memory");
}

// Prologue: depth-0 input projections + bias, px[b,g,row,n] (fp32) into ws.
__global__ __launch_bounds__(64) void proj0_kernel(
  const float* __restrict__ src, const float* __restrict__ trg,
  const float* __restrict__ Wix, const float* __restrict__ Wiy,
  const float* __restrict__ bx, const float* __restrict__ by,
  float* __restrict__ ws)
{
  const int row = blockIdx.x, g = blockIdx.y, b = blockIdx.z;
  const int n = threadIdx.x;
  const float* x = (g == 0) ? (src + (b*Sn + row)*Hn) : (trg + (b*Tn + row)*Hn);
  const float* W = (g == 0) ? Wix : Wiy;   // depth-0 slice
  float a = (g == 0) ? bx[n] : by[n];      // depth-0 bias folded in
  #pragma unroll 8
  for (int f = 0; f < Hn; ++f) a = fmaf(x[f], W[f*Hn + n], a);
  ws[((size_t)(b*2 + g)*Sn + row)*Hn + n] = a;
}

// Fused lag-1 wavefront, 1024 threads = 16 waves: wave = (g, nt, dep).
// VALID-REGION ONLY: block b runs sl+tl rounds; diagonals clipped to
// [max(0,d-tl+1), min(sl-1,d)]. Valid cells never depend on invalid ones
// (recurrence flows from smaller i,j); invalid region pre-zeroed by memset.
// All wave-uniform values readfirstlane'd -> per-round diag math is SALU;
// per-tile addressing = 1 v_add (SGPR + per-lane const) + scalar-bound clamp.
// Clamped (dead) lanes read in-bounds rows of zero-init'd fp16 state -> only
// corrupt MFMA columns >= nc, which are never written.
__global__ __launch_bounds__(1024, 1) void grid_rnn_fused(
  const float* __restrict__ Whx, const float* __restrict__ Why,
  const float* __restrict__ Wix, const float* __restrict__ Wiy,
  const float* __restrict__ bx,  const float* __restrict__ by,
  const int* __restrict__ src_lens, const int* __restrict__ trg_lens,
  float* __restrict__ out, const float* __restrict__ ws)
{
  extern __shared__ u16 smem[];
  char* const smemc = (char*)smem;
  const int b    = blockIdx.x;
  const int tid  = threadIdx.x;
  const int lane = tid & 63;
  const int wid  = __builtin_amdgcn_readfirstlane(tid >> 6);
  const int q    = lane >> 4;
  const int c    = lane & 15;
  const int dep  = wid & 1;
  const int nt   = (wid >> 1) & 3;
  const int g    = wid >> 3;
  const int sl = __builtin_amdgcn_readfirstlane(src_lens[b]);
  const int tl = __builtin_amdgcn_readfirstlane(trg_lens[b]);
  const int NB = sl + tl;   // rounds: diags 0..sl+tl-2 for dep0, lag 1 for dep1

  for (int idx = tid; idx < LDSB/4; idx += 1024) ((u32*)smem)[idx] = 0u;

  // ---- weights (own depth, own 16-feature tile), single fp16
  const float* Wh = (g == 0 ? Whx : Why) + dep*H2n*Hn;
  const int nb = nt*16 + c;
  i32x4 whf[4];
  #pragma unroll
  for (int kk = 0; kk < 4; ++kk){
    #pragma unroll
    for (int p = 0; p < 4; ++p){
      float w0 = Wh[(kk*32 + q*8 + 2*p    )*Hn + nb];
      float w1 = Wh[(kk*32 + q*8 + 2*p + 1)*Hn + nb];
      whf[kk][p] = (int)pack2f16(w0, w1);
    }
  }
  const float* Wi = (g == 0 ? Wix : Wiy) + Hn*Hn;  // depth-1 slice (dep1 only)
  i32x4 wif[2];
  #pragma unroll
  for (int kk = 0; kk < 2; ++kk){
    #pragma unroll
    for (int p = 0; p < 4; ++p){
      float w0 = Wi[(kk*32 + q*8 + 2*p    )*Hn + nb];
      float w1 = Wi[(kk*32 + q*8 + 2*p + 1)*Hn + nb];
      wif[kk][p] = (int)pack2f16(w0, w1);
    }
  }
  f32x4 bias4;  // depth-1 bias (dep0 gets bias via ws projections)
  {
    const float* bb = (g == 0 ? bx : by) + dep*Hn;
    #pragma unroll
    for (int r4 = 0; r4 < 4; ++r4) bias4[r4] = bb[nt*16 + q*4 + r4];
  }
  const char* const pxb = (const char*)(ws + (size_t)(b*2 + g)*Sn*Hn);
  char* const outb = (char*)(out + (size_t)((g*2 + dep)*Bn + b)*(size_t)(Sn*Tn)*Hn);

  // per-lane address parts (bytes), computed once
  const int plJ = q*16 - c*STRB;                    // j-indexed reads (X; P if g==0)
  const int plI = q*16 + c*STRB;                    // i-indexed reads (Y; P if g==1)
  const int plP = g ? plI : plJ;
  const int plW = (g ? c*STRB : -c*STRB) + nt*32 + q*8;
  const int plO = c*24320 + nt*64 + q*16;           // 24320 = 95*Hn*4 (out diag stride)
  const int plPx= (g ? -c*256 : c*256) + nt*64 + q*16;

  // smem layout per depth d at d*4*ARRB: [X p0][X p1][Y p0][Y p1]
  const int baseX = dep*4*ARRB;
  const int baseY = dep*4*ARRB + 2*ARRB;
  const int baseP = g ? 2*ARRB : 0;                 // dep0's X (g=0) / Y (g=1)
  const int baseW = dep*4*ARRB + (g ? 2*ARRB : 0);

  __syncthreads();   // init + weights visible

  for (int r = 0; r < NB; ++r){
    const int myd  = r - dep;
    const bool wact = (myd >= 0) && (myd <= NB - 2);
    const int cpB = (r & 1) ? ARRB : 0;     // write parity offset
    const int ppB = ARRB - cpB;             // read parity offset
    const int i0 = imax(0, myd - (tl - 1));
    const int i1 = imin(sl - 1, myd);
    const int nc = i1 - i0 + 1;
    const int mtiles = (nc + 15) >> 4;
    const int sJ = (myd - i0)*STRB;
    const int sI = i0*STRB;
    // scalar bases + clamp bounds (all SALU)
    const int aX  = baseX + ppB + sJ;
    const int loX = baseX + ppB + (myd - i1)*STRB;
    const int aY  = baseY + ppB + sI;
    const int hiY = baseY + ppB + i1*STRB + 48;
    const int aP  = baseP + ppB + (g ? sI : sJ);
    const int loP = baseP + ppB + (g ? sI : (myd - i1)*STRB);
    const int hiP = baseP + ppB + (g ? i1*STRB : sJ) + 48;
    const int aW  = baseW + cpB + (g ? sI : sJ);
    const int sO  = myd*256 + i0*24320;
    const int sPx = (g ? (myd - i0) : i0)*256;
    const int pxLo= (g ? (myd - i1) : i0)*256;
    const int pxHi= (g ? (myd - i0) : i1)*256 + 240;

    #pragma unroll
    for (int u = 0; u < 6; ++u){
      if (!(wact && u < mtiles)) continue;   // scalar branch (all operands SGPR)
      const int du = u*2304;                 // 16*STRB
      int vX = aX - du + plJ; vX = imax(vX, loX);
      int vY = aY + du + plI; vY = imin(vY, hiY);

      f32x4 acc;
      if (dep == 0){
        int vp = (g ? sPx - u*4096 : sPx + u*4096) + plPx;
        vp = imin(imax(vp, pxLo), pxHi);
        acc = *(const f32x4*)(pxb + (u32)vp);
      } else {
        acc = bias4;
      }
      // recurrence: K=128 (kk0-1: hx from col j; kk2-3: hy from row i)
      #pragma unroll
      for (int kk = 0; kk < 2; ++kk){
        i32x4 sv = *(const i32x4*)(smemc + (vX + kk*64));
        acc = __builtin_amdgcn_mfma_f32_16x16x32_f16(
                __builtin_bit_cast(f16x8, whf[kk]),
                __builtin_bit_cast(f16x8, sv), acc, 0, 0, 0);
      }
      #pragma unroll
      for (int kk = 0; kk < 2; ++kk){
        i32x4 sv = *(const i32x4*)(smemc + (vY + kk*64));
        acc = __builtin_amdgcn_mfma_f32_16x16x32_f16(
                __builtin_bit_cast(f16x8, whf[kk+2]),
                __builtin_bit_cast(f16x8, sv), acc, 0, 0, 0);
      }
      // depth-1 projection: dep0's h(i,j) from its previous-parity state slot
      if (dep == 1){
        int vP = aP + (g ? du : -du) + plP;
        vP = imin(imax(vP, loP), hiP);
        #pragma unroll
        for (int kk = 0; kk < 2; ++kk){
          i32x4 pv = *(const i32x4*)(smemc + (vP + kk*64));
          acc = __builtin_amdgcn_mfma_f32_16x16x32_f16(
                  __builtin_bit_cast(f16x8, wif[kk]),
                  __builtin_bit_cast(f16x8, pv), acc, 0, 0, 0);
        }
      }
      // tanh -> immediate state write (fp16, current parity) + out store.
      // No output mask needed: every computed cell is inside (sl x tl).
      float h0 = fast_tanh(acc[0]), h1 = fast_tanh(acc[1]);
      float h2 = fast_tanh(acc[2]), h3 = fast_tanh(acc[3]);
      if (c < nc - u*16){
        int vW = aW + (g ? du : -du) + plW;
        u32x2 hp; hp[0] = pack2f16(h0, h1); hp[1] = pack2f16(h2, h3);
        *(u32x2*)(smemc + vW) = hp;
        int vO = sO + u*389120 + plO;        // 389120 = 16*24320
        f32x4 ov = {h0, h1, h2, h3};
        *(f32x4*)(outb + (u32)vO) = ov;
      }
    }
    barrier_lds_only();   // single barrier per round (parity buffers)
  }
}

extern "C" void kernel_launch(void* const* d_in, const int* in_sizes, int n_in,
                              void* d_out, int out_size, void* d_ws, size_t ws_size,
                              hipStream_t stream) {
  (void)in_sizes; (void)n_in; (void)ws_size;
  (void)hipFuncSetAttribute((const void*)grid_rnn_fused,
                            hipFuncAttributeMaxDynamicSharedMemorySize, LDSB);
  // invalid region (i>=sl or j>=tl) must read as exact zeros; kernel only
  // writes the valid sub-grid.
  (void)hipMemsetAsync(d_out, 0, (size_t)out_size, stream);
  proj0_kernel<<<dim3(Sn, 2, Bn), 64, 0, stream>>>(
      (const float*)d_in[0], (const float*)d_in[1],
      (const float*)d_in[2], (const float*)d_in[5],
      (const float*)d_in[4], (const float*)d_in[7],
      (float*)d_ws);
  grid_rnn_fused<<<dim3(Bn), dim3(1024), LDSB, stream>>>(
      (const float*)d_in[3], (const float*)d_in[6],
      (const float*)d_in[2], (const float*)d_in[5],
      (const float*)d_in[4], (const float*)d_in[7],
      (const int*)d_in[8], (const int*)d_in[9],
      (float*)d_out, (const float*)d_ws);
}